// Round 7
// baseline (241.221 us; speedup 1.0000x reference)
//
#include <hip/hip_runtime.h>

// AR(24) rollout: out[b,t,d], t in [0,168), from last 24 timesteps of x[b,:,d].
//
// Graph anatomy: dur_us includes ~216 us of harness 0xAA fills (2 x 672 MiB
// at 6.5 TB/s -- the measured achievable ceiling). Kernel floor = 100.7 MB /
// 6.5 TB/s = 15.5 us; full-graph roofline ~232 us.
//
// Ladder (kernel-only us): scalar 23.4 | float2 NT 19.8 | float4 NT 27.0 |
// NT-vs-plain null (R7) | elementwise-fma (pk) null (R8).
// Two candidate models:
//   A (additive): kernel ~= per-SIMD FMA issue + drain@6.5TB/s; issue and
//     drain never overlap at 1 wave/SIMD.
//   M (overlapped): kernel ~= max(issue, 88MB/BW(width)), BW(512B)~4.45TB/s;
//     nothing left to gain.
// R9 discriminator: SAME R5 body (float2+NT, identical FMA order -> absmax
// 0.0), but 512-thread blocks x 128 blocks -> each block's 8 waves pack
// 2-per-SIMD on 128 CUs. Under A, a wave's vmcnt-cap stalls are filled by
// its SIMD-mate's FMA issue: kernel -> max(13.4 issue, 13.2 drain) ~14 us,
// dur ~231-232. Under M: null (~237) -> declare roofline.

#define BATCH 256
#define SEQ   336
#define DIMS  512
#define ORDER 24
#define TSEQ  168

typedef float f32x2 __attribute__((ext_vector_type(2)));

__global__ __launch_bounds__(512) void ar_rollout_kernel(
    const float* __restrict__ x,     // [BATCH, SEQ, DIMS]
    const float* __restrict__ W,     // [ORDER, 1]
    const float* __restrict__ bias,  // [1]
    float* __restrict__ out)         // [BATCH, TSEQ, DIMS]
{
    // One thread per (b, d-pair): d = 2*p, covers {d, d+1}.
    const int tid = blockIdx.x * blockDim.x + threadIdx.x;  // b*(DIMS/2) + p
    const int p = tid & (DIMS / 2 - 1);
    const int b = tid >> 8;          // tid / (DIMS/2)
    if (b >= BATCH) return;
    const int d = p * 2;

    // AR coefficients (wave-uniform -> scalar broadcasts) and bias.
    float wc[ORDER];
#pragma unroll
    for (int k = 0; k < ORDER; ++k) wc[k] = W[k];
    const float bb = bias[0];

    // Init window: x[b, SEQ-ORDER+k, {d,d+1}], k = 0..23 (oldest first).
    // Consecutive lanes = consecutive float2 -> each load is a coalesced
    // 512 B/wave dwordx2 burst.
    const f32x2* xp = (const f32x2*)(x + ((size_t)b * SEQ + (SEQ - ORDER)) * DIMS + d);
    f32x2 w[ORDER];
#pragma unroll
    for (int k = 0; k < ORDER; ++k) w[k] = xp[(size_t)k * (DIMS / 2)];

    // Rollout. At step j within a group, logical window element k lives in
    // physical register w[(j+k) % ORDER]; the new value overwrites w[j].
    // Two independent serial chains (x,y components), each with the exact
    // R0 FMA order (absmax 0.0); 2-way ILP keeps FMA issue dense.
    f32x2* op = (f32x2*)(out + (size_t)b * TSEQ * DIMS + d);
#pragma unroll 1
    for (int g = 0; g < TSEQ / ORDER; ++g) {
#pragma unroll
        for (int j = 0; j < ORDER; ++j) {
            float ya = bb;
            float yb = bb;
#pragma unroll
            for (int k = 0; k < ORDER; ++k) {
                const f32x2 wk = w[(j + k) % ORDER];
                ya = fmaf(wk.x, wc[k], ya);
                yb = fmaf(wk.y, wc[k], yb);
            }
            f32x2 y2;
            y2.x = ya;
            y2.y = yb;
            w[j] = y2;
            __builtin_nontemporal_store(y2, op);  // 88 MB stream, never re-read
            op += DIMS / 2;
        }
    }
}

extern "C" void kernel_launch(void* const* d_in, const int* in_sizes, int n_in,
                              void* d_out, int out_size, void* d_ws, size_t ws_size,
                              hipStream_t stream) {
    const float* x    = (const float*)d_in[0];
    const float* W    = (const float*)d_in[1];
    const float* bias = (const float*)d_in[2];
    // d_in[3] is tar_seq_len (==168), compile-time constant here.
    float* out = (float*)d_out;

    const int threads = 512;                           // 8 waves/block -> 2 waves/SIMD
    const int blocks  = (BATCH * DIMS / 2) / threads;  // 128 blocks on 128 CUs
    ar_rollout_kernel<<<blocks, threads, 0, stream>>>(x, W, bias, out);
}

// Round 8
// 235.974 us; speedup vs baseline: 1.0222x; 1.0222x over previous
//
#include <hip/hip_runtime.h>

// AR(24) rollout: out[b,t,d], t in [0,168), from last 24 timesteps of x[b,:,d].
//
// FINAL (R10 = restore of best-measured R5). Graph anatomy: dur_us includes
// ~216.4 us of harness 0xAA fills (2 x 672 MiB at 6.5 TB/s = 81-83% of HBM
// peak, the measured achievable ceiling). Kernel itself ~19.8 us.
//
// Ladder (kernel-only us): scalar 23.4 | float2 NT 19.8 (BEST) | float4 NT
// 27.0 | 2x-redundant-occupancy 34 (R3) | NT-vs-plain null (R7) |
// packed-FMA null (R8) | 2-waves/SIMD-on-128-CU 24.9 (R9, regressed).
// Confirmed model M: kernel ~= max(FMA issue, 88 MB / store-BW(width)),
// with the 512 B/wave dwordx2 NT stream at its pattern-specific BW ceiling
// (~4.5 TB/s). Wave count is pinned at 2048/width by the serial per-(b,d)
// AR chains (redundant-compute splitting refuted in R3); float2 minimizes
// the combination. Full graph sits within ~2% of the fill-BW-everywhere
// bound -> roofline.

#define BATCH 256
#define SEQ   336
#define DIMS  512
#define ORDER 24
#define TSEQ  168

typedef float f32x2 __attribute__((ext_vector_type(2)));

__global__ __launch_bounds__(256) void ar_rollout_kernel(
    const float* __restrict__ x,     // [BATCH, SEQ, DIMS]
    const float* __restrict__ W,     // [ORDER, 1]
    const float* __restrict__ bias,  // [1]
    float* __restrict__ out)         // [BATCH, TSEQ, DIMS]
{
    // One thread per (b, d-pair): d = 2*p, covers {d, d+1}.
    const int tid = blockIdx.x * blockDim.x + threadIdx.x;  // b*(DIMS/2) + p
    const int p = tid & (DIMS / 2 - 1);
    const int b = tid >> 8;          // tid / (DIMS/2)
    if (b >= BATCH) return;
    const int d = p * 2;

    // AR coefficients (wave-uniform -> scalar broadcasts) and bias.
    float wc[ORDER];
#pragma unroll
    for (int k = 0; k < ORDER; ++k) wc[k] = W[k];
    const float bb = bias[0];

    // Init window: x[b, SEQ-ORDER+k, {d,d+1}], k = 0..23 (oldest first).
    // Consecutive lanes = consecutive float2 -> each load is a coalesced
    // 512 B/wave dwordx2 burst.
    const f32x2* xp = (const f32x2*)(x + ((size_t)b * SEQ + (SEQ - ORDER)) * DIMS + d);
    f32x2 w[ORDER];
#pragma unroll
    for (int k = 0; k < ORDER; ++k) w[k] = xp[(size_t)k * (DIMS / 2)];

    // Rollout. At step j within a group, logical window element k lives in
    // physical register w[(j+k) % ORDER]; the new value overwrites w[j].
    // Two independent serial chains (x,y components), each with the exact
    // R0 FMA order (absmax 0.0); 2-way ILP keeps FMA issue dense.
    f32x2* op = (f32x2*)(out + (size_t)b * TSEQ * DIMS + d);
#pragma unroll 1
    for (int g = 0; g < TSEQ / ORDER; ++g) {
#pragma unroll
        for (int j = 0; j < ORDER; ++j) {
            float ya = bb;
            float yb = bb;
#pragma unroll
            for (int k = 0; k < ORDER; ++k) {
                const f32x2 wk = w[(j + k) % ORDER];
                ya = fmaf(wk.x, wc[k], ya);
                yb = fmaf(wk.y, wc[k], yb);
            }
            f32x2 y2;
            y2.x = ya;
            y2.y = yb;
            w[j] = y2;
            __builtin_nontemporal_store(y2, op);  // 88 MB stream, never re-read
            op += DIMS / 2;
        }
    }
}

extern "C" void kernel_launch(void* const* d_in, const int* in_sizes, int n_in,
                              void* d_out, int out_size, void* d_ws, size_t ws_size,
                              hipStream_t stream) {
    const float* x    = (const float*)d_in[0];
    const float* W    = (const float*)d_in[1];
    const float* bias = (const float*)d_in[2];
    // d_in[3] is tar_seq_len (==168), compile-time constant here.
    float* out = (float*)d_out;

    const int threads = 256;
    const int blocks  = (BATCH * DIMS / 2) / threads;  // 256 blocks, 1/CU
    ar_rollout_kernel<<<blocks, threads, 0, stream>>>(x, W, bias, out);
}